// Round 13
// baseline (2551.596 us; speedup 1.0000x reference)
//
#include <hip/hip_runtime.h>

// V=16000 E=512 H=512 L=2 S=128 T=128 B=64; gate dim 4H=2048
// r13 = r12 base (per-layer dataflow, write-once histories, flag store +
// lane-parallel poll, gate-blocked weights) plus:
//  (B) L1 merged step: ONE 64-lane poll (L0>=t+1 | own>=t) -> ONE 32-frag
//      load burst -> one vmcnt -> 32kc MFMA. (L0 keeps r12 structure:
//      X-phase before own-wait absorbs skew slack -- r11 proved hoisting
//      L0's wait regresses.)
//  (C) fused logits: grid=256 = 64 pipe WGs + 192 persistent gemm workers
//      (all co-resident -> no dispatch-order deadlock). Workers pop tiles
//      from an atomic queue, poll L1 flags (thr = min(130+2*tm,255); pad
//      slot 256 pre-zeroed), then run the 128x128 fp16 tile into d_out.
//      Requires outWb live during the pipe => ws ~84 MB, gated on ws_size;
//      fallback = r12 sequence (with B).

typedef __attribute__((ext_vector_type(8))) short v8s;
typedef __attribute__((ext_vector_type(4))) short v4s;
typedef __attribute__((ext_vector_type(8))) _Float16 v8h;
typedef __attribute__((ext_vector_type(4))) float v4f;
typedef __attribute__((ext_vector_type(4))) unsigned int v4u;

#define AS1 __attribute__((address_space(1)))
#define AS3 __attribute__((address_space(3)))

__device__ __forceinline__ short f2h(float x) {
  _Float16 h = (_Float16)x;
  return __builtin_bit_cast(short, h);
}
__device__ __forceinline__ void gload16(const void* g, void* l) {
  __builtin_amdgcn_global_load_lds((const AS1 void*)g, (AS3 void*)l, 16, 0, 0);
}
__device__ __forceinline__ float sigf(float x) { return 1.f / (1.f + __expf(-x)); }
__device__ __forceinline__ float tanhfast(float x) { return 2.f / (1.f + __expf(-2.f * x)) - 1.f; }

__device__ __forceinline__ void ld16_sc1(v4u& d, const void* p) {
  asm volatile("global_load_dwordx4 %0, %1, off sc1" : "=v"(d) : "v"(p) : "memory");
}
__device__ __forceinline__ void ld16(v4u& d, const void* p) {
  asm volatile("global_load_dwordx4 %0, %1, off" : "=v"(d) : "v"(p));
}

// lanes 0..31 check flags[(base+lane)*16] >= tgt (lanes>=32 auto-pass)
__device__ __forceinline__ void poll32(const unsigned* flags, int base, unsigned tgt) {
  int lane = threadIdx.x & 63;
  const unsigned* fp = flags + (size_t)(base + (lane & 31)) * 16;
  while (true) {
    unsigned v;
    asm volatile("global_load_dword %0, %1, off sc1\n\ts_waitcnt vmcnt(0)"
                 : "=v"(v) : "v"(fp) : "memory");
    if (__all((int)((lane >= 32) || (v >= tgt)))) break;
    __builtin_amdgcn_s_sleep(1);
  }
}
// 64-lane dual poll: lanes<32 -> L0 flag >= t+1 ; lanes>=32 -> L1 flag >= t
__device__ __forceinline__ void poll_dual(const unsigned* flags, int t) {
  int lane = threadIdx.x & 63;
  unsigned tgt = (lane < 32) ? (unsigned)(t + 1) : (unsigned)t;
  const unsigned* fp = flags + (size_t)lane * 16;
  while (true) {
    unsigned v;
    asm volatile("global_load_dword %0, %1, off sc1\n\ts_waitcnt vmcnt(0)"
                 : "=v"(v) : "v"(fp) : "memory");
    if (__all((int)(v >= tgt))) break;
    __builtin_amdgcn_s_sleep(1);
  }
}
// worker poll: lanes 0..31 check L1 flags >= thr (slow sleep)
__device__ __forceinline__ void poll_l1(const unsigned* flags, unsigned thr) {
  int lane = threadIdx.x & 63;
  const unsigned* fp = flags + (size_t)(32 + (lane & 31)) * 16;
  while (true) {
    unsigned v;
    asm volatile("global_load_dword %0, %1, off sc1\n\ts_waitcnt vmcnt(0)"
                 : "=v"(v) : "v"(fp) : "memory");
    if (__all((int)((lane >= 32) || (v >= thr)))) break;
    __builtin_amdgcn_s_sleep(16);
  }
}

// ---------- weight convert fp32->fp16 + gate-block reorder:
// input row r = g*512 + u  ->  rr = (u>>4)*64 + g*16 + (u&15)
__global__ void conv_w(const float* __restrict__ in, short* __restrict__ out,
                       int rows, int ldo, int coloff, int reorder) {
  int i = blockIdx.x * 256 + threadIdx.x;
  if (i >= rows * 128) return;
  int r = i >> 7, k4 = (i & 127) * 4;
  int rr = reorder ? (((r >> 4) & 31) * 64 + (r >> 9) * 16 + (r & 15)) : r;
  float4 v = *(const float4*)(in + (size_t)r * 512 + k4);
  v4s s; s[0] = f2h(v.x); s[1] = f2h(v.y); s[2] = f2h(v.z); s[3] = f2h(v.w);
  *(v4s*)(out + (size_t)rr * ldo + coloff + k4) = s;
}

__global__ void conv_b(const float* __restrict__ a, const float* __restrict__ b,
                       float* __restrict__ o) {
  int r = blockIdx.x * 256 + threadIdx.x;
  if (r < 2048) o[((r >> 4) & 31) * 64 + (r >> 9) * 16 + (r & 15)] = a[r] + b[r];
}

__global__ void embed_k(const int* __restrict__ ids, const float* __restrict__ emb,
                        short* __restrict__ out, int nvalid) {
  int row = blockIdx.x;
  int e = threadIdx.x * 2;
  float2 v = make_float2(0.f, 0.f);
  if (row < nvalid) {
    int id = ids[row];
    v = *(const float2*)(emb + (size_t)id * 512 + e);
  }
  unsigned pack = ((unsigned)(unsigned short)f2h(v.y) << 16) | (unsigned short)f2h(v.x);
  *(unsigned*)(out + (size_t)row * 512 + e) = pack;
}

__global__ void zero_k(short* p, int n) {
  int i = blockIdx.x * 256 + threadIdx.x;
  if (i < n) p[i] = 0;
}

#define GF_BIAS 2
#define GF_GUARDM 4
#define SLOT 32768

// ---------- gemm tile body (shared by standalone kernel and fused workers)
__device__ __forceinline__ void gemm_tile(
    const short* Abase, const short* Bbase, const float* bias, float* Cm,
    int M, int K, int ldc, int tm, int tn, int flags,
    short* lA, short* lB) {
  const int tid = threadIdx.x, lane = tid & 63, wave = tid >> 6;
  const int wm = wave >> 1, wn = wave & 1;
  v4f acc[4][4] = {};
  const short* At = Abase + (size_t)tm * 128 * K;
  const short* Bt = Bbase + (size_t)tn * 128 * K;

  for (int kt = 0; kt < K; kt += 64) {
    __syncthreads();
#pragma unroll
    for (int i2 = 0; i2 < 4; ++i2) {
      int c = (wave * 4 + i2) * 64 + lane;
      int row = c >> 3, ch = c & 7;
      int sch = ch ^ (row & 7);
      gload16(At + (size_t)row * K + kt + sch * 8, (char*)lA + (wave * 4 + i2) * 1024);
      gload16(Bt + (size_t)row * K + kt + sch * 8, (char*)lB + (wave * 4 + i2) * 1024);
    }
    asm volatile("s_waitcnt vmcnt(0)" ::: "memory");
    __syncthreads();
#pragma unroll
    for (int kc = 0; kc < 2; ++kc) {
      v8h af[4], bh[4];
#pragma unroll
      for (int mt = 0; mt < 4; ++mt) {
        int row = wm * 64 + mt * 16 + (lane & 15);
        af[mt] = *(const v8h*)((const char*)lA + row * 128 +
                               ((kc * 64 + (lane >> 4) * 16) ^ ((row & 7) << 4)));
      }
#pragma unroll
      for (int nt = 0; nt < 4; ++nt) {
        int row = wn * 64 + nt * 16 + (lane & 15);
        bh[nt] = *(const v8h*)((const char*)lB + row * 128 +
                               ((kc * 64 + (lane >> 4) * 16) ^ ((row & 7) << 4)));
      }
#pragma unroll
      for (int mt = 0; mt < 4; ++mt)
#pragma unroll
        for (int nt = 0; nt < 4; ++nt)
          acc[mt][nt] = __builtin_amdgcn_mfma_f32_16x16x32_f16(af[mt], bh[nt], acc[mt][nt], 0, 0, 0);
    }
  }

  const int rbase = tm * 128 + wm * 64 + (lane >> 4) * 4;
  const int cbase = tn * 128 + wn * 64 + (lane & 15);
#pragma unroll
  for (int mt = 0; mt < 4; ++mt) {
#pragma unroll
    for (int nt = 0; nt < 4; ++nt) {
      int gc = cbase + nt * 16;
      float bv = (flags & GF_BIAS) ? bias[gc] : 0.f;
#pragma unroll
      for (int rg = 0; rg < 4; ++rg) {
        int gr = rbase + mt * 16 + rg;
        if ((flags & GF_GUARDM) && gr >= M) continue;
        Cm[(size_t)gr * ldc + gc] = acc[mt][nt][rg] + bv;
      }
    }
  }
}

// ---------- standalone GEMM (fallback path)
__global__ __launch_bounds__(256, 2) void gemm_bt(
    const short* __restrict__ Am, const short* __restrict__ Bm,
    const float* __restrict__ bias, float* __restrict__ Cm,
    int M, int N, int K, int ldc, int flags) {
  __shared__ short lA[128 * 64];
  __shared__ short lB[128 * 64];
  gemm_tile(Am, Bm, bias, Cm, M, K, ldc, blockIdx.y, blockIdx.x, flags, lA, lB);
}

// ---------- fused pipe + logits workers
struct FusedArgs {
  const short* W0e;  // [2048][1024] fp16 [Wih|Whh], gate-block-reordered rows
  const short* W0d;
  const short* W1e;
  const short* W1d;
  const short* X;    // [255][64][512] fp16 embeddings
  const float* b0e;  // [2048] fp32, gate-block-reordered
  const float* b0d;
  const float* b1e;
  const float* b1d;
  short* h0;         // 256 slots (state s at slot s, write-once)
  short* h1;         // 257 slots (slot 256 = zero pad)
  unsigned* flags;   // [64] per-WG step flags, stride 16 dwords
  unsigned* wq;      // worker tile queue counter
  const short* Bgem; // outWb [16000][512] fp16 (valid only when workers run)
  const float* obias;
  float* Cout;       // d_out fp32 [8128][16000]
  int Tenc, Ttot;    // 128, 255
};

__global__ __launch_bounds__(256, 1) void lstm_fused(FusedArgs A) {
  __shared__ __align__(16) char smem[133120];
  const int tid = threadIdx.x, lane = tid & 63, wave = tid >> 6;
  const int bid = blockIdx.x;

  if (bid >= 64) {
    // ---------------- logits worker: pop tiles, gate on L1 flags ----------
    short* lA = (short*)smem;
    short* lB = (short*)(smem + 16384);
    int* sQ = (int*)(smem + 32768);
    while (true) {
      if (tid == 0)
        *sQ = (int)__hip_atomic_fetch_add(A.wq, 1u, __ATOMIC_RELAXED,
                                          __HIP_MEMORY_SCOPE_AGENT);
      __syncthreads();
      int id = *sQ;
      __syncthreads();
      if (id >= 8000) break;
      int tm = id / 125, tn = id - tm * 125;
      unsigned thr = 130 + 2 * tm; if (thr > 255) thr = 255;
      if (wave == 0) poll_l1(A.flags, thr);
      __syncthreads();
      gemm_tile(A.h1 + (size_t)129 * SLOT, A.Bgem, A.obias, A.Cout,
                8128, 512, 16000, tm, tn, GF_BIAS | GF_GUARDM, lA, lB);
    }
    return;
  }

  // ---------------- pipe WG ----------------
  short* Wlds = (short*)smem;                 // 128 KB
  short* hsm = (short*)(smem + 131072);       // 2 KB
  const int w = bid, layer = w >> 5, wl = w & 31;

  auto stage = [&](const short* Wsrc) {
    for (int i = tid * 8; i < 64 * 1024; i += 256 * 8) {
      int row = i >> 10, k = i & 1023;
      v8s v = *(const v8s*)(Wsrc + (size_t)row * 1024 + k);
      *(v8s*)((char*)Wlds + row * 2048 + ((k * 2) ^ ((row & 7) << 4))) = v;
    }
  };
  stage((layer ? A.W1e : A.W0e) + (size_t)(wl * 64) * 1024);

  const int uu = lane & 15;
  float beV[4], bdV[4];
#pragma unroll
  for (int g = 0; g < 4; ++g) {
    beV[g] = (layer ? A.b1e : A.b0e)[wl * 64 + g * 16 + uu];
    bdV[g] = (layer ? A.b1d : A.b0d)[wl * 64 + g * 16 + uu];
  }
  float creg[4] = {0.f, 0.f, 0.f, 0.f};

  const int arow = wave * 16 + uu;
  const int koff = (lane >> 4) * 8;
  const size_t aoff = (size_t)arow * 512 + koff;
  __syncthreads();

  for (int t = 0; t < A.Ttot; ++t) {
    if (t == A.Tenc) {
      stage((layer ? A.W1d : A.W0d) + (size_t)(wl * 64) * 1024);
      __syncthreads();
    }

    v4f acc[4] = {};

    if (layer) {
      // (B) merged: one poll, one 32-frag burst, one vmcnt, 32kc MFMA
      if (wave == 0) poll_dual(A.flags, t);
      __syncthreads();
      const short* p1 = A.h0 + (size_t)(t + 1) * SLOT + aoff;
      const short* p2 = A.h1 + (size_t)t * SLOT + aoff;
      v4u fl[32];
#pragma unroll
      for (int kc = 0; kc < 16; ++kc) ld16_sc1(fl[kc], p1 + kc * 32);
#pragma unroll
      for (int kc = 0; kc < 16; ++kc) ld16_sc1(fl[16 + kc], p2 + kc * 32);
      asm volatile("s_waitcnt vmcnt(0)" ::: "memory");
      __builtin_amdgcn_sched_barrier(0);
#pragma unroll
      for (int kc = 0; kc < 32; ++kc) {
        v8h af = __builtin_bit_cast(v8h, fl[kc]);
        int kg = kc * 32 + koff;
#pragma unroll
        for (int nt = 0; nt < 4; ++nt) {
          int wrow = nt * 16 + uu;
          v8h bh = *(const v8h*)((const char*)Wlds + wrow * 2048 +
                                 ((kg * 2) ^ ((wrow & 7) << 4)));
          acc[nt] = __builtin_amdgcn_mfma_f32_16x16x32_f16(af, bh, acc[nt], 0, 0, 0);
        }
      }
    } else {
      // L0 r12 structure: X-phase (slack) then own-wait + h-phase
      {
        const short* p1 = A.X + (size_t)t * SLOT + aoff;
        v4u fa[16];
#pragma unroll
        for (int kc = 0; kc < 16; ++kc) ld16(fa[kc], p1 + kc * 32);
        asm volatile("s_waitcnt vmcnt(0)" ::: "memory");
        __builtin_amdgcn_sched_barrier(0);
#pragma unroll
        for (int kc = 0; kc < 16; ++kc) {
          v8h af = __builtin_bit_cast(v8h, fa[kc]);
          int kg = kc * 32 + koff;
#pragma unroll
          for (int nt = 0; nt < 4; ++nt) {
            int wrow = nt * 16 + uu;
            v8h bh = *(const v8h*)((const char*)Wlds + wrow * 2048 +
                                   ((kg * 2) ^ ((wrow & 7) << 4)));
            acc[nt] = __builtin_amdgcn_mfma_f32_16x16x32_f16(af, bh, acc[nt], 0, 0, 0);
          }
        }
      }
      if (t > 0) {
        if (wave == 0) poll32(A.flags, 0, (unsigned)t);
        __syncthreads();
      }
      {
        const short* p2 = A.h0 + (size_t)t * SLOT + aoff;
        v4u fb[16];
#pragma unroll
        for (int kc = 0; kc < 16; ++kc) ld16_sc1(fb[kc], p2 + kc * 32);
        asm volatile("s_waitcnt vmcnt(0)" ::: "memory");
        __builtin_amdgcn_sched_barrier(0);
#pragma unroll
        for (int kc = 0; kc < 16; ++kc) {
          v8h af = __builtin_bit_cast(v8h, fb[kc]);
          int kg = (kc + 16) * 32 + koff;
#pragma unroll
          for (int nt = 0; nt < 4; ++nt) {
            int wrow = nt * 16 + uu;
            v8h bh = *(const v8h*)((const char*)Wlds + wrow * 2048 +
                                   ((kg * 2) ^ ((wrow & 7) << 4)));
            acc[nt] = __builtin_amdgcn_mfma_f32_16x16x32_f16(af, bh, acc[nt], 0, 0, 0);
          }
        }
      }
    }

    // activation directly from acc
    {
      const bool enc = t < A.Tenc;
      const float b0v = enc ? beV[0] : bdV[0];
      const float b1v = enc ? beV[1] : bdV[1];
      const float b2v = enc ? beV[2] : bdV[2];
      const float b3v = enc ? beV[3] : bdV[3];
#pragma unroll
      for (int rg = 0; rg < 4; ++rg) {
        float g0 = acc[0][rg] + b0v;
        float g1 = acc[1][rg] + b1v;
        float g2 = acc[2][rg] + b2v;
        float g3 = acc[3][rg] + b3v;
        float c = sigf(g1) * creg[rg] + sigf(g0) * tanhfast(g2);
        creg[rg] = c;
        float h = sigf(g3) * tanhfast(c);
        int bb = wave * 16 + ((lane >> 4) << 2) + rg;
        hsm[bb * 16 + uu] = f2h(h);
      }
    }
    __syncthreads();

    // publish state t+1 (write-once): sc1 stores, drain, sync, flag
    if (tid < 128) {
      int b = tid >> 1, half = tid & 1;
      v4u d = *(const v4u*)(&hsm[b * 16 + half * 8]);
      short* dst = (layer ? A.h1 : A.h0) + (size_t)(t + 1) * SLOT
                   + b * 512 + wl * 16 + half * 8;
      asm volatile("global_store_dwordx4 %0, %1, off sc1" :: "v"(dst), "v"(d) : "memory");
    }
    asm volatile("s_waitcnt vmcnt(0)" ::: "memory");
    __syncthreads();
    if (tid == 0) {
      unsigned val = (unsigned)(t + 1);
      const unsigned* fp = A.flags + (size_t)w * 16;
      asm volatile("global_store_dword %0, %1, off sc1" :: "v"(fp), "v"(val) : "memory");
    }
  }
}

extern "C" void kernel_launch(void* const* d_in, const int* in_sizes, int n_in,
                              void* d_out, int out_size, void* d_ws, size_t ws_size,
                              hipStream_t stream) {
  (void)in_sizes; (void)n_in; (void)out_size;
  const int* src = (const int*)d_in[0];
  const int* trg = (const int*)d_in[1];
  const float* enc_emb = (const float*)d_in[3];
  const float* dec_emb = (const float*)d_in[4];
  const float* enc_Wih = (const float*)d_in[5];
  const float* enc_Whh = (const float*)d_in[6];
  const float* enc_bih = (const float*)d_in[7];
  const float* enc_bhh = (const float*)d_in[8];
  const float* dec_Wih = (const float*)d_in[9];
  const float* dec_Whh = (const float*)d_in[10];
  const float* dec_bih = (const float*)d_in[11];
  const float* dec_bhh = (const float*)d_in[12];
  const float* out_W = (const float*)d_in[13];
  const float* out_b = (const float*)d_in[14];

  char* p = (char*)d_ws;
  auto alloc = [&](size_t sz) { char* r = p; p += (sz + 255) & ~(size_t)255; return r; };
  short* H0 = (short*)alloc((size_t)256 * SLOT * 2);       // 16.78 MB
  short* H1 = (short*)alloc((size_t)257 * SLOT * 2);       // 16.84 MB
  short* W0e = (short*)alloc((size_t)2048 * 1024 * 2);
  short* W0d = (short*)alloc((size_t)2048 * 1024 * 2);
  short* W1e = (short*)alloc((size_t)2048 * 1024 * 2);
  short* W1d = (short*)alloc((size_t)2048 * 1024 * 2);
  short* XO = (short*)alloc((size_t)255 * SLOT * 2);       // 16.71 MB
  float* bE0 = (float*)alloc(2048 * 4);
  float* bE1 = (float*)alloc(2048 * 4);
  float* bD0 = (float*)alloc(2048 * 4);
  float* bD1 = (float*)alloc(2048 * 4);
  unsigned* flags = (unsigned*)alloc(8192);                // flags 4KB + wq
  unsigned* wq = flags + 1024;
  size_t common = (size_t)(p - (char*)d_ws);
  const size_t outWbBytes = (size_t)16000 * 512 * 2;
  bool fused = (ws_size >= common + outWbBytes + 65536);
  short* outWb = fused ? (short*)alloc(outWbBytes) : XO;   // fallback overlays X

  // zero: h0 s0, h1 s0, h1 pad slot 256, flags+wq
  zero_k<<<128, 256, 0, stream>>>(H0, 32768);
  zero_k<<<128, 256, 0, stream>>>(H1, 32768);
  zero_k<<<128, 256, 0, stream>>>(H1 + (size_t)256 * SLOT, 32768);
  zero_k<<<16, 256, 0, stream>>>((short*)flags, 4096);

  // weight conversion / reorder: [Wih | Whh] concat, gate-blocked rows
  conv_w<<<1024, 256, 0, stream>>>(enc_Wih, W0e, 2048, 1024, 0, 1);
  conv_w<<<1024, 256, 0, stream>>>(enc_Whh, W0e, 2048, 1024, 512, 1);
  conv_w<<<1024, 256, 0, stream>>>(dec_Wih, W0d, 2048, 1024, 0, 1);
  conv_w<<<1024, 256, 0, stream>>>(dec_Whh, W0d, 2048, 1024, 512, 1);
  conv_w<<<1024, 256, 0, stream>>>(enc_Wih + (size_t)2048 * 512, W1e, 2048, 1024, 0, 1);
  conv_w<<<1024, 256, 0, stream>>>(enc_Whh + (size_t)2048 * 512, W1e, 2048, 1024, 512, 1);
  conv_w<<<1024, 256, 0, stream>>>(dec_Wih + (size_t)2048 * 512, W1d, 2048, 1024, 0, 1);
  conv_w<<<1024, 256, 0, stream>>>(dec_Whh + (size_t)2048 * 512, W1d, 2048, 1024, 512, 1);
  conv_b<<<8, 256, 0, stream>>>(enc_bih, enc_bhh, bE0);
  conv_b<<<8, 256, 0, stream>>>(enc_bih + 2048, enc_bhh + 2048, bE1);
  conv_b<<<8, 256, 0, stream>>>(dec_bih, dec_bhh, bD0);
  conv_b<<<8, 256, 0, stream>>>(dec_bih + 2048, dec_bhh + 2048, bD1);

  // embeddings
  embed_k<<<8192, 256, 0, stream>>>(src, enc_emb, XO, 8192);
  embed_k<<<8128, 256, 0, stream>>>(trg, dec_emb, XO + (size_t)8192 * 512, 8128);

  FusedArgs fa = {W0e, W0d, W1e, W1d, XO, bE0, bD0, bE1, bD1,
                  H0, H1, flags, wq, outWb, out_b, (float*)d_out, 128, 255};

  if (fused) {
    // outWb ready before the merged kernel; workers consume H1 as published
    conv_w<<<8000, 256, 0, stream>>>(out_W, outWb, 16000, 512, 0, 0);
    lstm_fused<<<256, 256, 0, stream>>>(fa);
  } else {
    lstm_fused<<<64, 256, 0, stream>>>(fa);   // pipe only
    conv_w<<<8000, 256, 0, stream>>>(out_W, outWb, 16000, 512, 0, 0);
    gemm_bt<<<dim3(125, 64), 256, 0, stream>>>(H1 + (size_t)129 * SLOT, outWb, out_b,
                                               (float*)d_out, 8128, 16000, 512, 16000,
                                               GF_BIAS | GF_GUARDM);
  }
}